// Round 4
// baseline (127.834 us; speedup 1.0000x reference)
//
#include <hip/hip_runtime.h>
#include <hip/hip_bf16.h>
#include <math.h>

// GAT layer B=8, N=2048, F=64 on gfx950.
// Round 4: k_attn = 8-wave blocks (16 waves/CU), barrier-free main loop,
// register-resident P (A-fragment owner generates P), j-split across waves
// reduced once via LDS at the end. whtg B-frags L1-shared between wave pairs.

#define NN 2048
#define BB 8
#define ALPHA 0.2f

typedef __attribute__((ext_vector_type(8))) short s8v;   // 8 bf16 = 4 VGPRs
typedef __attribute__((ext_vector_type(4))) float f4v;

static __device__ __forceinline__ unsigned pk_bf16(float lo, float hi) {
  __hip_bfloat162 t = __float22bfloat162_rn(float2{lo, hi});
  return *(unsigned*)&t;
}

// ---------------- Kernel 1: fused adj-bitmask (blocks 0..511) + Wh/e1/e2 ----------------
__global__ __launch_bounds__(256) void k_pre(
    const float* __restrict__ adj, const float* __restrict__ h,
    const float* __restrict__ W, const float* __restrict__ a,
    unsigned long long* __restrict__ adjq, unsigned short* __restrict__ whtg,
    float* __restrict__ e1, float* __restrict__ e2) {
  const int t = threadIdx.x, lane = t & 63, w = t >> 6;

  if (blockIdx.x < 512) {
    // ---- adj -> bit rows: 4 rows/block, 1 wave/row, 32 ballots ----
    const int row = blockIdx.x * 4 + w;
    const float* ar = adj + (size_t)row * NN;
    unsigned long long* aq = adjq + row * 32;
    #pragma unroll
    for (int it = 0; it < 32; ++it) {
      unsigned long long m = __ballot(ar[it * 64 + lane] > 0.f);
      if (lane == 0) aq[it] = m;
    }
    return;
  }

  // ---- Wh (bf16, transposed [B,64,N]) + e1,e2 ; 64 rows/block ----
  __shared__ __align__(16) float hsAll[64][68];
  __shared__ __align__(16) unsigned short Ws[64][72];
  const int rowBase = (blockIdx.x - 512) * 64;
  const int b = rowBase >> 11, n0 = rowBase & (NN - 1);

  float wr[64];                                  // W row `lane` (o = lane)
  #pragma unroll
  for (int k = 0; k < 16; ++k)
    *(f4v*)&wr[k * 4] = *(const f4v*)&W[lane * 64 + k * 4];

  #pragma unroll
  for (int qq = 0; qq < 4; ++qq) {
    const int idx = t + 256 * qq;                // 1024 float4s
    const int r = idx >> 4, c = (idx & 15) * 4;
    *(f4v*)&hsAll[r][c] = *(const f4v*)&h[(size_t)(rowBase + r) * 64 + c];
  }
  const float a1v = a[lane], a2v = a[64 + lane];
  __syncthreads();

  #pragma unroll
  for (int g = 0; g < 2; ++g) {                  // two 8-row ILP groups/wave
    const int r0 = w * 16 + g * 8;
    float acc[8];
    #pragma unroll
    for (int rr = 0; rr < 8; ++rr) acc[rr] = 0.f;
    #pragma unroll
    for (int f4i = 0; f4i < 16; ++f4i) {
      f4v hv[8];
      #pragma unroll
      for (int rr = 0; rr < 8; ++rr)
        hv[rr] = *(const f4v*)&hsAll[r0 + rr][f4i * 4];   // lane-uniform: broadcast
      #pragma unroll
      for (int x = 0; x < 4; ++x) {
        const float wv = wr[f4i * 4 + x];
        #pragma unroll
        for (int rr = 0; rr < 8; ++rr) acc[rr] = fmaf(hv[rr][x], wv, acc[rr]);
      }
    }
    #pragma unroll
    for (int p = 0; p < 4; ++p)
      *(unsigned*)&Ws[lane][r0 + p * 2] = pk_bf16(acc[p * 2], acc[p * 2 + 1]);

    float s1[8], s2[8];
    #pragma unroll
    for (int rr = 0; rr < 8; ++rr) { s1[rr] = acc[rr] * a1v; s2[rr] = acc[rr] * a2v; }
    #pragma unroll
    for (int m = 1; m < 64; m <<= 1)
      #pragma unroll
      for (int rr = 0; rr < 8; ++rr) {
        s1[rr] += __shfl_xor(s1[rr], m);
        s2[rr] += __shfl_xor(s2[rr], m);
      }
    if (lane == 0)
      #pragma unroll
      for (int rr = 0; rr < 8; ++rr) {
        e1[rowBase + r0 + rr] = s1[rr];
        e2[rowBase + r0 + rr] = s2[rr];
      }
  }
  __syncthreads();

  // transposed coalesced store: thread -> (o = t>>2, 16 j's)
  const int o = t >> 2, seg = t & 3;
  const s8v v0 = *(const s8v*)&Ws[o][seg * 16];
  const s8v v1 = *(const s8v*)&Ws[o][seg * 16 + 8];
  unsigned short* dst = whtg + ((size_t)(b * 64 + o) << 11) + n0 + seg * 16;
  *(s8v*)dst = v0;
  *(s8v*)(dst + 8) = v1;
}

// ---------------- Kernel 2: fused attention ----------------
// Grid (N/32, B) = (64,8), 512 thr (8 waves). Wave: i_sub = w>>2 (16 rows),
// jq = w&3 (8 j-tiles). Barrier-free loop; one LDS reduction at the end.
__global__ __launch_bounds__(512, 4) void k_attn(
    const unsigned long long* __restrict__ adjq,
    const unsigned short* __restrict__ whtg,
    const float* __restrict__ e1g, const float* __restrict__ e2g,
    float* __restrict__ out) {
  __shared__ __align__(16) float pc[8][16][68];   // partial C, padded (34 KB)
  __shared__ float ls[8][16];                     // partial rowsums

  const int t = threadIdx.x, lane = t & 63, w = t >> 6;
  const int q = lane >> 4, l15 = lane & 15;
  const int i_sub = w >> 2, jq = w & 3;
  const int b = blockIdx.y;
  const int i0 = blockIdx.x * 32;
  const size_t bN = (size_t)b * NN;
  const int iw0 = i0 + i_sub * 16;

  const float e1v = e1g[bN + iw0 + l15];
  const unsigned long long* arow = adjq + (size_t)(iw0 + l15) * 32 + jq * 8;
  const unsigned short* wb = whtg + ((size_t)b << 17);

  f4v acc[4];
  #pragma unroll
  for (int s = 0; s < 4; ++s) acc[s] = f4v{0.f, 0.f, 0.f, 0.f};
  float psum = 0.f;

  // tile-0 scalar prefetch
  unsigned long long am = arow[0];
  f4v e2r[4];
  {
    const int j0 = jq * 512;
    #pragma unroll
    for (int ks = 0; ks < 2; ++ks)
      #pragma unroll
      for (int hh = 0; hh < 2; ++hh)
        e2r[ks * 2 + hh] = *(const f4v*)&e2g[bN + j0 + ks * 32 + q * 8 + hh * 4];
  }

  for (int k = 0; k < 8; ++k) {
    const int j0 = jq * 512 + k * 64;
    // B-fragments (waves w and w^4 read identical addresses -> L1 reuse)
    s8v bfr[8];
    #pragma unroll
    for (int s = 0; s < 4; ++s)
      #pragma unroll
      for (int ks = 0; ks < 2; ++ks)
        bfr[s * 2 + ks] =
            *(const s8v*)(wb + (((size_t)(s * 16 + l15)) << 11) + j0 + ks * 32 + q * 8);

    // P-gen in registers -> A-fragments (thread owns A[m=l15][k=q*8+jj])
    s8v af[2];
    #pragma unroll
    for (int ks = 0; ks < 2; ++ks) {
      const unsigned bits = (unsigned)(am >> (ks * 32 + q * 8)) & 0xffu;
      float p[8];
      #pragma unroll
      for (int jj = 0; jj < 8; ++jj) {
        const float s = e1v + e2r[ks * 2 + (jj >> 2)][jj & 3];
        const float lr = fmaxf(s, ALPHA * s);
        const float pv = ((bits >> jj) & 1u) ? __expf(lr) : 0.f;
        p[jj] = pv;
        psum += pv;
      }
      union { s8v v; unsigned u[4]; } cv;
      cv.u[0] = pk_bf16(p[0], p[1]);
      cv.u[1] = pk_bf16(p[2], p[3]);
      cv.u[2] = pk_bf16(p[4], p[5]);
      cv.u[3] = pk_bf16(p[6], p[7]);
      af[ks] = cv.v;
    }

    if (k < 7) {                                  // next-tile scalar prefetch
      am = arow[k + 1];
      const int jn = j0 + 64;
      #pragma unroll
      for (int ks = 0; ks < 2; ++ks)
        #pragma unroll
        for (int hh = 0; hh < 2; ++hh)
          e2r[ks * 2 + hh] = *(const f4v*)&e2g[bN + jn + ks * 32 + q * 8 + hh * 4];
    }

    #pragma unroll
    for (int s = 0; s < 4; ++s) {
      acc[s] = __builtin_amdgcn_mfma_f32_16x16x32_bf16(af[0], bfr[s * 2 + 0], acc[s], 0, 0, 0);
      acc[s] = __builtin_amdgcn_mfma_f32_16x16x32_bf16(af[1], bfr[s * 2 + 1], acc[s], 0, 0, 0);
    }
  }

  // wave-local rowsum over q, then stash partials
  psum += __shfl_xor(psum, 16);
  psum += __shfl_xor(psum, 32);
  if (lane < 16) ls[w][lane] = psum;
  #pragma unroll
  for (int s = 0; s < 4; ++s)
    #pragma unroll
    for (int r = 0; r < 4; ++r)
      pc[w][q * 4 + r][s * 16 + l15] = acc[s][r];
  __syncthreads();

  // cross-wave j-reduction + epilogue: thread t -> row t>>4, 4 cols
  const int row = t >> 4, c0 = (t & 15) * 4;
  const int ise = row >> 4, rl = row & 15;
  f4v sum = *(const f4v*)&pc[ise * 4 + 0][rl][c0];
  #pragma unroll
  for (int j = 1; j < 4; ++j) {
    const f4v pv = *(const f4v*)&pc[ise * 4 + j][rl][c0];
    sum += pv;
  }
  const float rsum = ls[ise * 4 + 0][rl] + ls[ise * 4 + 1][rl] +
                     ls[ise * 4 + 2][rl] + ls[ise * 4 + 3][rl];
  f4v o;
  #pragma unroll
  for (int x = 0; x < 4; ++x) {
    float v = sum[x] / rsum;
    o[x] = v > 0.f ? v : expm1f(v);
  }
  *(f4v*)&out[(bN + i0 + row) * 64 + c0] = o;
}

extern "C" void kernel_launch(void* const* d_in, const int* in_sizes, int n_in,
                              void* d_out, int out_size, void* d_ws, size_t ws_size,
                              hipStream_t stream) {
  (void)in_sizes; (void)n_in; (void)out_size; (void)ws_size;
  const float* h   = (const float*)d_in[0];
  const float* adj = (const float*)d_in[1];
  const float* W   = (const float*)d_in[2];
  const float* a   = (const float*)d_in[3];
  float* outp = (float*)d_out;

  // ws carve: whtg 2 MB | e1 64 KB | e2 64 KB | adjq 512 KB
  unsigned short* whtg = (unsigned short*)d_ws;
  float* e1 = (float*)((char*)d_ws + (size_t)BB * 64 * NN * 2);
  float* e2 = e1 + (size_t)BB * NN;
  unsigned long long* adjq = (unsigned long long*)(e2 + (size_t)BB * NN);

  k_pre<<<768, 256, 0, stream>>>(adj, h, W, a, adjq, whtg, e1, e2);
  k_attn<<<dim3(NN / 32, BB), 512, 0, stream>>>(adjq, whtg, e1, e2, outp);
}

// Round 5
// 118.253 us; speedup vs baseline: 1.0810x; 1.0810x over previous
//
#include <hip/hip_runtime.h>
#include <hip/hip_bf16.h>
#include <math.h>

// GAT layer B=8, N=2048, F=64 on gfx950.
// Round 5: k_attn with register-double-buffered B-fragments (launch_bounds
// (256,2) -> no load serialization; R3's VGPR=56 starvation showed 13 serial
// 250-cyc L2 loads/tile = 43 us), 4-way j-split for occupancy, LDS reduce.
// P stays register-resident (A-fragment owner generates P). k_wh at 2
// blocks/CU; k_adj at 4 blocks/CU.

#define NN 2048
#define BB 8
#define ALPHA 0.2f

typedef __attribute__((ext_vector_type(8))) short s8v;   // 8 bf16 = 4 VGPRs
typedef __attribute__((ext_vector_type(4))) float f4v;

static __device__ __forceinline__ unsigned pk_bf16(float lo, float hi) {
  __hip_bfloat162 t = __float22bfloat162_rn(float2{lo, hi});
  return *(unsigned*)&t;
}

// ---------------- Kernel 1: adj -> 64-bit masks ----------------
// 1024 blocks x 256 thr: 2 rows/block, wave w -> (row-half), 16 ballots.
__global__ __launch_bounds__(256) void k_adj(const float* __restrict__ adj,
                                             unsigned long long* __restrict__ adjq) {
  const int t = threadIdx.x, lane = t & 63, w = t >> 6;
  const int row = blockIdx.x * 2 + (w >> 1);
  const int half = w & 1;
  const float* ar = adj + (size_t)row * NN + half * 1024;
  unsigned long long* aq = adjq + row * 32 + half * 16;
  #pragma unroll
  for (int it = 0; it < 16; ++it) {
    unsigned long long m = __ballot(ar[it * 64 + lane] > 0.f);
    if (lane == 0) aq[it] = m;
  }
}

// ---------------- Kernel 2: Wh (bf16, transposed [B,64,N]) + e1,e2 ----------------
// 512 blocks x 256 thr, 32 rows/block (2 blocks/CU).
__global__ __launch_bounds__(256, 2) void k_wh(
    const float* __restrict__ h, const float* __restrict__ W,
    const float* __restrict__ a, unsigned short* __restrict__ whtg,
    float* __restrict__ e1, float* __restrict__ e2) {
  __shared__ __align__(16) float hs[32][68];            // 8.7 KB
  __shared__ __align__(16) unsigned short Ws[64][40];   // 5.1 KB, 80B rows (16B-aligned)
  const int t = threadIdx.x, lane = t & 63, w = t >> 6;
  const int rowBase = blockIdx.x * 32;
  const int b = rowBase >> 11, n0 = rowBase & (NN - 1);

  float wr[64];                                  // W row `lane` (o = lane)
  #pragma unroll
  for (int k = 0; k < 16; ++k)
    *(f4v*)&wr[k * 4] = *(const f4v*)&W[lane * 64 + k * 4];

  #pragma unroll
  for (int qq = 0; qq < 2; ++qq) {
    const int idx = t + 256 * qq;                // 512 float4s
    const int r = idx >> 4, c = (idx & 15) * 4;
    *(f4v*)&hs[r][c] = *(const f4v*)&h[(size_t)(rowBase + r) * 64 + c];
  }
  const float a1v = a[lane], a2v = a[64 + lane];
  __syncthreads();

  const int r0 = w * 8;                          // 8 rows per wave, ILP chains
  float acc[8];
  #pragma unroll
  for (int rr = 0; rr < 8; ++rr) acc[rr] = 0.f;
  #pragma unroll
  for (int f4i = 0; f4i < 16; ++f4i) {
    f4v hv[8];
    #pragma unroll
    for (int rr = 0; rr < 8; ++rr)
      hv[rr] = *(const f4v*)&hs[r0 + rr][f4i * 4];      // lane-uniform broadcast
    #pragma unroll
    for (int x = 0; x < 4; ++x) {
      const float wv = wr[f4i * 4 + x];
      #pragma unroll
      for (int rr = 0; rr < 8; ++rr) acc[rr] = fmaf(hv[rr][x], wv, acc[rr]);
    }
  }
  #pragma unroll
  for (int p = 0; p < 4; ++p)
    *(unsigned*)&Ws[lane][r0 + p * 2] = pk_bf16(acc[p * 2], acc[p * 2 + 1]);

  float s1[8], s2[8];
  #pragma unroll
  for (int rr = 0; rr < 8; ++rr) { s1[rr] = acc[rr] * a1v; s2[rr] = acc[rr] * a2v; }
  #pragma unroll
  for (int m = 1; m < 64; m <<= 1)
    #pragma unroll
    for (int rr = 0; rr < 8; ++rr) {
      s1[rr] += __shfl_xor(s1[rr], m);
      s2[rr] += __shfl_xor(s2[rr], m);
    }
  if (lane == 0)
    #pragma unroll
    for (int rr = 0; rr < 8; ++rr) {
      e1[rowBase + r0 + rr] = s1[rr];
      e2[rowBase + r0 + rr] = s2[rr];
    }
  __syncthreads();

  // transposed coalesced store: thread -> (o = t>>2, 8 rows)
  const int o = t >> 2, seg = t & 3;
  const s8v v = *(const s8v*)&Ws[o][seg * 8];
  *(s8v*)(whtg + ((size_t)(b * 64 + o) << 11) + n0 + seg * 8) = v;
}

// ---------------- Kernel 3: fused attention ----------------
// Grid (N/16, B) = (128, 8) = 1024 blocks, 256 thr (4 waves).
// All waves share the block's 16 i-rows; wave w walks j-quarter w (8 tiles).
// B-frags register-double-buffered from L2; P in registers; LDS j-reduce.
__global__ __launch_bounds__(256, 2) void k_attn(
    const unsigned long long* __restrict__ adjq,
    const unsigned short* __restrict__ whtg,
    const float* __restrict__ e1g, const float* __restrict__ e2g,
    float* __restrict__ out) {
  __shared__ __align__(16) float e2row[NN];       //  8 KB
  __shared__ __align__(16) float pc[4][16][68];   // 17.4 KB
  __shared__ float ls[4][16];

  const int t = threadIdx.x, lane = t & 63, w = t >> 6;
  const int q = lane >> 4, l15 = lane & 15;
  const int b = blockIdx.y;
  const int i0 = blockIdx.x * 16;
  const size_t bN = (size_t)b * NN;

  // stage full e2 row for this batch
  #pragma unroll
  for (int kk = 0; kk < 2; ++kk) {
    const int idx = (t + 256 * kk) * 4;
    *(f4v*)&e2row[idx] = *(const f4v*)&e2g[bN + idx];
  }

  const float e1v = e1g[bN + i0 + l15];
  const unsigned long long* arow = adjq + (size_t)(i0 + l15) * 32 + w * 8;
  const unsigned short* wb = whtg + ((size_t)b << 17);
  const int jbase = w * 512;

  f4v acc[4];
  #pragma unroll
  for (int s = 0; s < 4; ++s) acc[s] = f4v{0.f, 0.f, 0.f, 0.f};
  float psum = 0.f;

  // register prefetch of tile 0 (8 independent 16B loads + adj word)
  s8v bf[8];
  #pragma unroll
  for (int s = 0; s < 4; ++s)
    #pragma unroll
    for (int ks = 0; ks < 2; ++ks)
      bf[s * 2 + ks] =
          *(const s8v*)(wb + (((size_t)(s * 16 + l15)) << 11) + jbase + ks * 32 + q * 8);
  unsigned long long am = arow[0];

  __syncthreads();   // e2row visible

  #pragma unroll
  for (int k = 0; k < 8; ++k) {
    const int j0 = jbase + k * 64;
    // rotate current tile into `cur`, issue next tile's loads immediately
    s8v cur[8];
    #pragma unroll
    for (int x = 0; x < 8; ++x) cur[x] = bf[x];
    const unsigned long long amc = am;
    if (k < 7) {
      const int jn = j0 + 64;
      #pragma unroll
      for (int s = 0; s < 4; ++s)
        #pragma unroll
        for (int ks = 0; ks < 2; ++ks)
          bf[s * 2 + ks] =
              *(const s8v*)(wb + (((size_t)(s * 16 + l15)) << 11) + jn + ks * 32 + q * 8);
      am = arow[k + 1];
    }

    // P-gen in registers (thread owns A[m=l15][k=q*8+jj])
    s8v af[2];
    #pragma unroll
    for (int ks = 0; ks < 2; ++ks) {
      const unsigned bits = (unsigned)(amc >> (ks * 32 + q * 8)) & 0xffu;
      const f4v ea = *(const f4v*)&e2row[j0 + ks * 32 + q * 8];
      const f4v eb = *(const f4v*)&e2row[j0 + ks * 32 + q * 8 + 4];
      float p[8];
      #pragma unroll
      for (int jj = 0; jj < 8; ++jj) {
        const float s = e1v + (jj < 4 ? ea[jj & 3] : eb[jj & 3]);
        const float lr = fmaxf(s, ALPHA * s);
        const float pv = ((bits >> jj) & 1u) ? __expf(lr) : 0.f;
        p[jj] = pv;
        psum += pv;
      }
      union { s8v v; unsigned u[4]; } cv;
      cv.u[0] = pk_bf16(p[0], p[1]);
      cv.u[1] = pk_bf16(p[2], p[3]);
      cv.u[2] = pk_bf16(p[4], p[5]);
      cv.u[3] = pk_bf16(p[6], p[7]);
      af[ks] = cv.v;
    }

    #pragma unroll
    for (int s = 0; s < 4; ++s) {
      acc[s] = __builtin_amdgcn_mfma_f32_16x16x32_bf16(af[0], cur[s * 2 + 0], acc[s], 0, 0, 0);
      acc[s] = __builtin_amdgcn_mfma_f32_16x16x32_bf16(af[1], cur[s * 2 + 1], acc[s], 0, 0, 0);
    }
  }

  // wave-local rowsum over q; stash partial C and partial rowsums
  psum += __shfl_xor(psum, 16);
  psum += __shfl_xor(psum, 32);
  if (lane < 16) ls[w][lane] = psum;
  #pragma unroll
  for (int s = 0; s < 4; ++s)
    #pragma unroll
    for (int r = 0; r < 4; ++r)
      pc[w][q * 4 + r][s * 16 + l15] = acc[s][r];
  __syncthreads();

  // cross-wave j-reduction + epilogue: thread t -> row t>>4, 4 cols
  const int row = t >> 4, c0 = (t & 15) * 4;
  f4v sum = *(const f4v*)&pc[0][row][c0];
  #pragma unroll
  for (int j = 1; j < 4; ++j) sum += *(const f4v*)&pc[j][row][c0];
  const float rsum = ls[0][row] + ls[1][row] + ls[2][row] + ls[3][row];
  f4v o;
  #pragma unroll
  for (int x = 0; x < 4; ++x) {
    float v = sum[x] / rsum;
    o[x] = v > 0.f ? v : expm1f(v);
  }
  *(f4v*)&out[(bN + i0 + row) * 64 + c0] = o;
}

extern "C" void kernel_launch(void* const* d_in, const int* in_sizes, int n_in,
                              void* d_out, int out_size, void* d_ws, size_t ws_size,
                              hipStream_t stream) {
  (void)in_sizes; (void)n_in; (void)out_size; (void)ws_size;
  const float* h   = (const float*)d_in[0];
  const float* adj = (const float*)d_in[1];
  const float* W   = (const float*)d_in[2];
  const float* a   = (const float*)d_in[3];
  float* outp = (float*)d_out;

  // ws carve: whtg 2 MB | e1 64 KB | e2 64 KB | adjq 512 KB
  unsigned short* whtg = (unsigned short*)d_ws;
  float* e1 = (float*)((char*)d_ws + (size_t)BB * 64 * NN * 2);
  float* e2 = e1 + (size_t)BB * NN;
  unsigned long long* adjq = (unsigned long long*)(e2 + (size_t)BB * NN);

  k_adj<<<NN / 2, 256, 0, stream>>>(adj, adjq);
  k_wh<<<(BB * NN) / 32, 256, 0, stream>>>(h, W, a, whtg, e1, e2);
  k_attn<<<dim3(NN / 16, BB), 256, 0, stream>>>(adjq, whtg, e1, e2, outp);
}

// Round 6
// 101.833 us; speedup vs baseline: 1.2553x; 1.1612x over previous
//
#include <hip/hip_runtime.h>
#include <hip/hip_bf16.h>
#include <math.h>

// GAT layer B=8, N=2048, F=64 on gfx950.
// Round 6: Wh stored in MFMA-fragment-SWIZZLED layout whswz[b][jt][frag][lane][8]
// so k_attn B-fragment loads are perfectly coalesced (R5's 48us k_attn was
// L1-throughput-bound: [o][j] layout put 4KB between lanes -> 64 cache lines
// per load instr). k_wh writes the swizzle directly from registers (no LDS
// transpose). P stays register-resident; 4-way j-split; LDS reduce at end.

#define NN 2048
#define BB 8
#define ALPHA 0.2f

typedef __attribute__((ext_vector_type(8))) short s8v;   // 8 bf16 = 4 VGPRs
typedef __attribute__((ext_vector_type(4))) float f4v;

static __device__ __forceinline__ unsigned pk_bf16(float lo, float hi) {
  __hip_bfloat162 t = __float22bfloat162_rn(float2{lo, hi});
  return *(unsigned*)&t;
}

// ---------------- Kernel 1: adj -> 64-bit masks ----------------
// 1024 blocks x 256 thr: 2 rows/block, wave -> half row, 16 ballots. HBM-bound.
__global__ __launch_bounds__(256) void k_adj(const float* __restrict__ adj,
                                             unsigned long long* __restrict__ adjq) {
  const int t = threadIdx.x, lane = t & 63, w = t >> 6;
  const int row = blockIdx.x * 2 + (w >> 1);
  const int half = w & 1;
  const float* ar = adj + (size_t)row * NN + half * 1024;
  unsigned long long* aq = adjq + row * 32 + half * 16;
  #pragma unroll
  for (int it = 0; it < 16; ++it) {
    unsigned long long m = __ballot(ar[it * 64 + lane] > 0.f);
    if (lane == 0) aq[it] = m;
  }
}

// ---------------- Kernel 2: Wh -> swizzled bf16 + e1,e2 ----------------
// 512 blocks x 256 thr, 32 n-rows/block. Wave w computes n-rows w*8..w*8+7
// for all 64 o (o = lane); that is exactly swizzle chunk (frag=(lane>>4)*2+ks,
// lane'=w*16+(lane&15)), stored straight from registers.
__global__ __launch_bounds__(256, 2) void k_wh(
    const float* __restrict__ h, const float* __restrict__ W,
    const float* __restrict__ a, unsigned short* __restrict__ whswz,
    float* __restrict__ e1, float* __restrict__ e2) {
  __shared__ __align__(16) float hs[32][68];            // 8.7 KB
  const int t = threadIdx.x, lane = t & 63, w = t >> 6;
  const int rowBase = blockIdx.x * 32;
  const int b = rowBase >> 11, n0 = rowBase & (NN - 1);
  const int jt = n0 >> 6, ks = (n0 >> 5) & 1;

  float wr[64];                                  // W row `lane` (o = lane)
  #pragma unroll
  for (int k = 0; k < 16; ++k)
    *(f4v*)&wr[k * 4] = *(const f4v*)&W[lane * 64 + k * 4];

  #pragma unroll
  for (int qq = 0; qq < 2; ++qq) {
    const int idx = t + 256 * qq;                // 512 float4s
    const int r = idx >> 4, c = (idx & 15) * 4;
    *(f4v*)&hs[r][c] = *(const f4v*)&h[(size_t)(rowBase + r) * 64 + c];
  }
  const float a1v = a[lane], a2v = a[64 + lane];
  __syncthreads();

  const int r0 = w * 8;                          // 8 n-rows per wave
  float acc[8];
  #pragma unroll
  for (int rr = 0; rr < 8; ++rr) acc[rr] = 0.f;
  #pragma unroll
  for (int f4i = 0; f4i < 16; ++f4i) {
    f4v hv[8];
    #pragma unroll
    for (int rr = 0; rr < 8; ++rr)
      hv[rr] = *(const f4v*)&hs[r0 + rr][f4i * 4];      // lane-uniform broadcast
    #pragma unroll
    for (int x = 0; x < 4; ++x) {
      const float wv = wr[f4i * 4 + x];
      #pragma unroll
      for (int rr = 0; rr < 8; ++rr) acc[rr] = fmaf(hv[rr][x], wv, acc[rr]);
    }
  }

  // swizzled store straight from registers (16B per thread)
  {
    union { s8v v; unsigned u[4]; } cv;
    cv.u[0] = pk_bf16(acc[0], acc[1]);
    cv.u[1] = pk_bf16(acc[2], acc[3]);
    cv.u[2] = pk_bf16(acc[4], acc[5]);
    cv.u[3] = pk_bf16(acc[6], acc[7]);
    unsigned short* dst = whswz + ((size_t)b << 17) + (jt << 12) +
                          ((((lane >> 4) << 1) + ks) << 9) +
                          ((w * 16 + (lane & 15)) << 3);
    *(s8v*)dst = cv.v;
  }

  float s1[8], s2[8];
  #pragma unroll
  for (int rr = 0; rr < 8; ++rr) { s1[rr] = acc[rr] * a1v; s2[rr] = acc[rr] * a2v; }
  #pragma unroll
  for (int m = 1; m < 64; m <<= 1)
    #pragma unroll
    for (int rr = 0; rr < 8; ++rr) {
      s1[rr] += __shfl_xor(s1[rr], m);
      s2[rr] += __shfl_xor(s2[rr], m);
    }
  if (lane == 0)
    #pragma unroll
    for (int rr = 0; rr < 8; ++rr) {
      e1[rowBase + r0 + rr] = s1[rr];
      e2[rowBase + r0 + rr] = s2[rr];
    }
}

// ---------------- Kernel 3: fused attention ----------------
// Grid (N/16, B) = (128, 8) = 1024 blocks, 256 thr (4 waves).
// Wave w walks j-quarter w (8 tiles of 64). B-frags: 8 coalesced 1KB loads
// per tile from the swizzled layout. P in registers; LDS j-reduce at end.
__global__ __launch_bounds__(256, 2) void k_attn(
    const unsigned long long* __restrict__ adjq,
    const unsigned short* __restrict__ whswz,
    const float* __restrict__ e1g, const float* __restrict__ e2g,
    float* __restrict__ out) {
  __shared__ __align__(16) float e2row[NN];       //  8 KB
  __shared__ __align__(16) float pc[4][16][68];   // 17.4 KB
  __shared__ float ls[4][16];

  const int t = threadIdx.x, lane = t & 63, w = t >> 6;
  const int q = lane >> 4, l15 = lane & 15;
  const int b = blockIdx.y;
  const int i0 = blockIdx.x * 16;
  const size_t bN = (size_t)b * NN;

  // stage full e2 row for this batch
  #pragma unroll
  for (int kk = 0; kk < 2; ++kk) {
    const int idx = (t + 256 * kk) * 4;
    *(f4v*)&e2row[idx] = *(const f4v*)&e2g[bN + idx];
  }

  const float e1v = e1g[bN + i0 + l15];
  const unsigned long long* arow = adjq + (size_t)(i0 + l15) * 32 + w * 8;
  // this wave's j-quarter: tiles jt = w*8 + k
  const unsigned short* tbase = whswz + ((size_t)b << 17) + ((size_t)(w * 8) << 12);
  const int jbase = w * 512;

  f4v acc[4];
  #pragma unroll
  for (int s = 0; s < 4; ++s) acc[s] = f4v{0.f, 0.f, 0.f, 0.f};
  float psum = 0.f;

  // register prefetch of tile 0: 8 coalesced 16B loads + adj word
  s8v bf[8];
  #pragma unroll
  for (int f = 0; f < 8; ++f)
    bf[f] = *(const s8v*)(tbase + (f << 9) + (lane << 3));
  unsigned long long am = arow[0];

  __syncthreads();   // e2row visible

  #pragma unroll
  for (int k = 0; k < 8; ++k) {
    const int j0 = jbase + k * 64;
    s8v cur[8];
    #pragma unroll
    for (int x = 0; x < 8; ++x) cur[x] = bf[x];
    const unsigned long long amc = am;
    if (k < 7) {
      const unsigned short* nb = tbase + ((k + 1) << 12);
      #pragma unroll
      for (int f = 0; f < 8; ++f)
        bf[f] = *(const s8v*)(nb + (f << 9) + (lane << 3));
      am = arow[k + 1];
    }

    // P-gen in registers (thread owns A[m=l15][k=q*8+jj])
    s8v af[2];
    #pragma unroll
    for (int ks = 0; ks < 2; ++ks) {
      const unsigned bits = (unsigned)(amc >> (ks * 32 + q * 8)) & 0xffu;
      const f4v ea = *(const f4v*)&e2row[j0 + ks * 32 + q * 8];
      const f4v eb = *(const f4v*)&e2row[j0 + ks * 32 + q * 8 + 4];
      float p[8];
      #pragma unroll
      for (int jj = 0; jj < 8; ++jj) {
        const float s = e1v + (jj < 4 ? ea[jj & 3] : eb[jj & 3]);
        const float lr = fmaxf(s, ALPHA * s);
        const float pv = ((bits >> jj) & 1u) ? __expf(lr) : 0.f;
        p[jj] = pv;
        psum += pv;
      }
      union { s8v v; unsigned u[4]; } cv;
      cv.u[0] = pk_bf16(p[0], p[1]);
      cv.u[1] = pk_bf16(p[2], p[3]);
      cv.u[2] = pk_bf16(p[4], p[5]);
      cv.u[3] = pk_bf16(p[6], p[7]);
      af[ks] = cv.v;
    }

    #pragma unroll
    for (int s = 0; s < 4; ++s) {
      acc[s] = __builtin_amdgcn_mfma_f32_16x16x32_bf16(af[0], cur[s * 2 + 0], acc[s], 0, 0, 0);
      acc[s] = __builtin_amdgcn_mfma_f32_16x16x32_bf16(af[1], cur[s * 2 + 1], acc[s], 0, 0, 0);
    }
  }

  // wave-local rowsum over q; stash partial C and partial rowsums
  psum += __shfl_xor(psum, 16);
  psum += __shfl_xor(psum, 32);
  if (lane < 16) ls[w][lane] = psum;
  #pragma unroll
  for (int s = 0; s < 4; ++s)
    #pragma unroll
    for (int r = 0; r < 4; ++r)
      pc[w][q * 4 + r][s * 16 + l15] = acc[s][r];
  __syncthreads();

  // cross-wave j-reduction + epilogue: thread t -> row t>>4, 4 cols
  const int row = t >> 4, c0 = (t & 15) * 4;
  f4v sum = *(const f4v*)&pc[0][row][c0];
  #pragma unroll
  for (int j = 1; j < 4; ++j) sum += *(const f4v*)&pc[j][row][c0];
  const float rsum = ls[0][row] + ls[1][row] + ls[2][row] + ls[3][row];
  f4v o;
  #pragma unroll
  for (int x = 0; x < 4; ++x) {
    float v = sum[x] / rsum;
    o[x] = v > 0.f ? v : expm1f(v);
  }
  *(f4v*)&out[(bN + i0 + row) * 64 + c0] = o;
}

extern "C" void kernel_launch(void* const* d_in, const int* in_sizes, int n_in,
                              void* d_out, int out_size, void* d_ws, size_t ws_size,
                              hipStream_t stream) {
  (void)in_sizes; (void)n_in; (void)out_size; (void)ws_size;
  const float* h   = (const float*)d_in[0];
  const float* adj = (const float*)d_in[1];
  const float* W   = (const float*)d_in[2];
  const float* a   = (const float*)d_in[3];
  float* outp = (float*)d_out;

  // ws carve: whswz 2 MB | e1 64 KB | e2 64 KB | adjq 512 KB
  unsigned short* whswz = (unsigned short*)d_ws;
  float* e1 = (float*)((char*)d_ws + (size_t)BB * 64 * NN * 2);
  float* e2 = e1 + (size_t)BB * NN;
  unsigned long long* adjq = (unsigned long long*)(e2 + (size_t)BB * NN);

  k_adj<<<NN / 2, 256, 0, stream>>>(adj, adjq);
  k_wh<<<(BB * NN) / 32, 256, 0, stream>>>(h, W, a, whswz, e1, e2);
  k_attn<<<dim3(NN / 16, BB), 256, 0, stream>>>(adjq, whswz, e1, e2, outp);
}